// Round 5
// baseline (12377.584 us; speedup 1.0000x reference)
//
#include <hip/hip_runtime.h>
#include <hip/hip_bf16.h>
#include <math.h>

// ---- problem dims ----
constexpr int NB   = 32;
constexpr int NS   = 256;
constexpr int NLC  = 16;
constexpr int NWD  = 256;
constexpr int NCD  = 124;
constexpr int NCO  = 32;
constexpr int NPOS = 36;
constexpr int NENR = 7;
constexpr int NH   = 512;
constexpr int NT   = 18;
constexpr int NIN0 = 331;
constexpr int NIN0P= 352;    // padded to x32 for BK=32
constexpr int NIN1 = 1024;
constexpr int NBS  = NB*NS;  // 8192
constexpr int NG4  = 4*NH;   // 2048
constexpr int NHID = 128;
constexpr int NCHUNK = 16;   // unit-chunks per dir (32 units each)

typedef __attribute__((ext_vector_type(8))) short short8v;
typedef __attribute__((ext_vector_type(4))) float f32x4;

__device__ __forceinline__ float sigmoidf_(float x){ return 1.0f/(1.0f+expf(-x)); }
__device__ __forceinline__ short f2bf(float f) {
    union { __hip_bfloat16 h; short s; } u;
    u.h = __float2bfloat16(f);
    return u.s;
}
__device__ __forceinline__ float bf2f(short s) {
    union { unsigned u; float f; } v;
    v.u = ((unsigned)(unsigned short)s) << 16;
    return v.f;
}
__device__ __forceinline__ unsigned packbf3(float v) {
    short hi = f2bf(v);
    short lo = f2bf(v - bf2f(hi));
    return ((unsigned)(unsigned short)hi << 16) | (unsigned short)lo;
}
// 8 packed u32 (elems k..k+7) -> hi/lo bf16 fragments
__device__ __forceinline__ void unpack8(const unsigned* w, short8v& hi, short8v& lo) {
    union U { short8v s; unsigned u[4]; } H, L;
    #pragma unroll
    for (int i = 0; i < 4; i++) {
        H.u[i] = (w[2*i+1] & 0xFFFF0000u) | (w[2*i] >> 16);
        L.u[i] = (w[2*i+1] << 16) | (w[2*i] & 0xFFFFu);
    }
    hi = H.s; lo = L.s;
}

// ---------------- features: word embed + char CNN + concat + relu -> packed u32 ----
__global__ __launch_bounds__(128) void k_features(const int* __restrict__ x_word,
    const float* __restrict__ x_pos, const int* __restrict__ x_char,
    const float* __restrict__ x_enr, const float* __restrict__ wembW,
    const float* __restrict__ cembW, const float* __restrict__ cnnW,
    const float* __restrict__ cnnb, unsigned* __restrict__ xout)
{
    __shared__ float ce[NLC][NCD];
    __shared__ float cv[NCO][13];
    __shared__ float cpool[NCO];
    int n = blockIdx.x;
    int tid = threadIdx.x;
    for (int i = tid; i < NLC*NCD; i += 128) {
        int l = i / NCD, c = i % NCD;
        ce[l][c] = cembW[x_char[n*NLC + l]*NCD + c];
    }
    __syncthreads();
    for (int p = tid; p < NCO*12; p += 128) {
        int o = p & 31, t = p >> 5;
        const float* wr = cnnW + o*NCD*5;
        float acc = 0.f;
        for (int c = 0; c < NCD; c++) {
            #pragma unroll
            for (int k = 0; k < 5; k++) acc += ce[t+k][c] * wr[c*5+k];
        }
        cv[o][t] = acc;
    }
    __syncthreads();
    if (tid < NCO) {
        float m = cv[tid][0];
        #pragma unroll
        for (int t = 1; t < 12; t++) m = fmaxf(m, cv[tid][t]);
        cpool[tid] = m + cnnb[tid];
    }
    __syncthreads();
    int widx = x_word[n];
    unsigned* xr = xout + (size_t)n * NIN0P;
    for (int j = tid; j < NIN0P; j += 128) {
        float v;
        if (j < NWD)            v = wembW[(size_t)widx*NWD + j];
        else if (j < NWD+NPOS)  v = x_pos[n*NPOS + (j-NWD)];
        else if (j < NWD+NPOS+NCO) v = cpool[j-(NWD+NPOS)];
        else if (j < NIN0)      v = x_enr[n*NENR + (j-(NWD+NPOS+NCO))];
        else                    v = 0.f;   // K pad
        xr[j] = packbf3(fmaxf(v, 0.f));
    }
}

// ---------------- pack f32 weight [N][Ksrc] -> packed u32 [N][Kdst] (zero pad) ----
__global__ void k_pack_w(const float* __restrict__ W, unsigned* __restrict__ out,
                         int N, int Ksrc, int Kdst)
{
    int idx = blockIdx.x*256 + threadIdx.x;
    if (idx >= N*Kdst) return;
    int n = idx / Kdst, k = idx % Kdst;
    float v = (k < Ksrc) ? W[(size_t)n*Ksrc + k] : 0.f;
    out[idx] = packbf3(v);
}

// ---------------- bf16x3 MFMA GEMM: C[M,N] = A@W^T + bias ----------------
// A,W packed u32 (hi|lo). 128x128 tile, BK=32, 256 thr (4 waves, 2x2 of 64x64).
constexpr int TBK = 32;
constexpr int LSTR = 36;   // LDS row stride (u32), pad 4 breaks bank conflicts
__global__ __launch_bounds__(256, 2) void k_gemm_bf3(
    const unsigned* __restrict__ A, const unsigned* __restrict__ W,
    const float* __restrict__ bias, float* __restrict__ C,
    int M, int N, int K)
{
    __shared__ unsigned Asl[128*LSTR];
    __shared__ unsigned Bsl[128*LSTR];
    int bm = blockIdx.x*128, bn = blockIdx.y*128;
    int tid = threadIdx.x;
    int l = tid & 63, wv = tid >> 6;
    int wm = wv >> 1, wn = wv & 1;
    int lr = l & 15, lk = l >> 4;

    f32x4 acc[4][4];
    #pragma unroll
    for (int i = 0; i < 4; i++)
        #pragma unroll
        for (int j = 0; j < 4; j++) acc[i][j] = (f32x4){0.f,0.f,0.f,0.f};

    uint4 ra[4], rb[4];
    int KT = K / TBK;
    // preload kt=0
    #pragma unroll
    for (int i = 0; i < 4; i++) {
        int idx = i*256 + tid, row = idx >> 3, c4 = (idx & 7)*4;
        ra[i] = *(const uint4*)(A + (size_t)(bm+row)*K + c4);
        rb[i] = *(const uint4*)(W + (size_t)(bn+row)*K + c4);
    }
    for (int kt = 0; kt < KT; kt++) {
        #pragma unroll
        for (int i = 0; i < 4; i++) {
            int idx = i*256 + tid, row = idx >> 3, c4 = (idx & 7)*4;
            *(uint4*)&Asl[row*LSTR + c4] = ra[i];
            *(uint4*)&Bsl[row*LSTR + c4] = rb[i];
        }
        __syncthreads();
        if (kt+1 < KT) {
            #pragma unroll
            for (int i = 0; i < 4; i++) {
                int idx = i*256 + tid, row = idx >> 3, c4 = (idx & 7)*4;
                ra[i] = *(const uint4*)(A + (size_t)(bm+row)*K + (kt+1)*TBK + c4);
                rb[i] = *(const uint4*)(W + (size_t)(bn+row)*K + (kt+1)*TBK + c4);
            }
        }
        short8v Ah[4], Al_[4], Bh[4], Bl[4];
        #pragma unroll
        for (int f = 0; f < 4; f++) {
            unsigned w8[8];
            int rowA = wm*64 + f*16 + lr;
            *(uint4*)&w8[0] = *(const uint4*)&Asl[rowA*LSTR + lk*8];
            *(uint4*)&w8[4] = *(const uint4*)&Asl[rowA*LSTR + lk*8 + 4];
            unpack8(w8, Ah[f], Al_[f]);
            int rowB = wn*64 + f*16 + lr;
            *(uint4*)&w8[0] = *(const uint4*)&Bsl[rowB*LSTR + lk*8];
            *(uint4*)&w8[4] = *(const uint4*)&Bsl[rowB*LSTR + lk*8 + 4];
            unpack8(w8, Bh[f], Bl[f]);
        }
        #pragma unroll
        for (int i = 0; i < 4; i++)
            #pragma unroll
            for (int j = 0; j < 4; j++) {
                acc[i][j] = __builtin_amdgcn_mfma_f32_16x16x32_bf16(Ah[i],  Bh[j], acc[i][j], 0, 0, 0);
                acc[i][j] = __builtin_amdgcn_mfma_f32_16x16x32_bf16(Al_[i], Bh[j], acc[i][j], 0, 0, 0);
                acc[i][j] = __builtin_amdgcn_mfma_f32_16x16x32_bf16(Ah[i],  Bl[j], acc[i][j], 0, 0, 0);
            }
        __syncthreads();
    }
    #pragma unroll
    for (int i = 0; i < 4; i++) {
        int m0 = bm + wm*64 + i*16 + lk*4;
        #pragma unroll
        for (int j = 0; j < 4; j++) {
            int n0 = bn + wn*64 + j*16 + lr;
            float bv = bias[n0];
            #pragma unroll
            for (int q = 0; q < 4; q++)
                C[(size_t)(m0+q)*N + n0] = acc[i][j][q] + bv;
        }
    }
}

// ---------------- persistent LSTM layer: 16 chunks x 2 dirs, 8 waves/block ----
// Split-bf16 weight-stationary MFMA recurrence; packed-u32 h exchange;
// per-chunk release flags; wave-parallel acquire poll; zx reg-prefetch.
__global__ __launch_bounds__(512, 2) void k_lstm_layer(
    const float* __restrict__ zx_f, const float* __restrict__ zx_b,
    const float* __restrict__ Whh_f, const float* __restrict__ Whh_b,
    unsigned* __restrict__ hpack, unsigned* __restrict__ hbf,
    unsigned* __restrict__ flags)
{
    int chunk = blockIdx.x;        // 0..15 (32 hidden units each)
    int dir   = blockIdx.y;
    int tid = threadIdx.x;
    int wv = tid >> 6, l = tid & 63;
    int g  = wv >> 1, hf = wv & 1; // gate, unit-half
    int lr = l & 15, lk = l >> 4;
    const float* zx  = dir ? zx_b  : zx_f;
    const float* Whh = dir ? Whh_b : Whh_f;
    unsigned* hb = hbf + (size_t)dir * (2*NB*NH);     // [slot][b][k] packed u32
    unsigned* flag = flags + (size_t)dir * NCHUNK * 16;

    // ---- preload this wave's 16 Whh gate-rows, split hi/lo bf16 ----
    short8v bwh[16], bwl[16];
    {
        const float* wrow = Whh + ((size_t)(g*NH + chunk*32 + hf*16 + lr))*NH + lk*8;
        #pragma unroll
        for (int kt = 0; kt < 16; kt++) {
            float u[8];
            *(float4*)&u[0] = *(const float4*)(wrow + kt*32);
            *(float4*)&u[4] = *(const float4*)(wrow + kt*32 + 4);
            short8v sh, sl;
            #pragma unroll
            for (int j = 0; j < 8; j++) {
                short hi = f2bf(u[j]);
                sh[j] = hi;
                sl[j] = f2bf(u[j] - bf2f(hi));
            }
            bwh[kt] = sh; bwl[kt] = sl;
        }
    }
    __shared__ float zsh[4][NB][32];
    float c0 = 0.f, c1 = 0.f;

    for (int t = 0; t < NS; t++) {
        int t_eff = dir ? (NS-1-t) : t;

        // ---- prefetch zx (independent of the flag) ----
        float pz[2][4];
        #pragma unroll
        for (int cc = 0; cc < 2; cc++) {
            int cell = tid + cc*512, b = cell >> 5, u = cell & 31;
            const float* zr = zx + ((size_t)(b*NS + t_eff))*NG4 + chunk*32 + u;
            #pragma unroll
            for (int g2 = 0; g2 < 4; g2++) pz[cc][g2] = zr[g2*NH];
        }

        f32x4 a0hh = {0,0,0,0}, a0lh = {0,0,0,0}, a0hl = {0,0,0,0};
        f32x4 a1hh = {0,0,0,0}, a1lh = {0,0,0,0}, a1hl = {0,0,0,0};
        if (t > 0) {
            {
                const unsigned* fp = &flag[(l & 15)*16];
                unsigned v;
                do {
                    v = __hip_atomic_load(fp, __ATOMIC_ACQUIRE,
                                          __HIP_MEMORY_SCOPE_AGENT);
                } while (!__all((int)(v >= (unsigned)t)));
            }
            const unsigned* hp = hb + ((t-1)&1)*(NB*NH);
            #pragma unroll
            for (int kt = 0; kt < 16; kt++) {
                const unsigned* p0 = hp + lr*NH      + kt*32 + lk*8;
                const unsigned* p1 = hp + (16+lr)*NH + kt*32 + lk*8;
                unsigned w0[8], w1[8];
                *(uint4*)&w0[0] = *(const uint4*)p0;
                *(uint4*)&w0[4] = *(const uint4*)(p0+4);
                *(uint4*)&w1[0] = *(const uint4*)p1;
                *(uint4*)&w1[4] = *(const uint4*)(p1+4);
                short8v a0h, a0l, a1h, a1l;
                unpack8(w0, a0h, a0l);
                unpack8(w1, a1h, a1l);
                a0hh = __builtin_amdgcn_mfma_f32_16x16x32_bf16(a0h, bwh[kt], a0hh, 0, 0, 0);
                a0lh = __builtin_amdgcn_mfma_f32_16x16x32_bf16(a0l, bwh[kt], a0lh, 0, 0, 0);
                a0hl = __builtin_amdgcn_mfma_f32_16x16x32_bf16(a0h, bwl[kt], a0hl, 0, 0, 0);
                a1hh = __builtin_amdgcn_mfma_f32_16x16x32_bf16(a1h, bwh[kt], a1hh, 0, 0, 0);
                a1lh = __builtin_amdgcn_mfma_f32_16x16x32_bf16(a1l, bwh[kt], a1lh, 0, 0, 0);
                a1hl = __builtin_amdgcn_mfma_f32_16x16x32_bf16(a1h, bwl[kt], a1hl, 0, 0, 0);
            }
        }
        // C layout: col = lane&15 -> unit hf*16+lr, row = lk*4+j -> batch
        #pragma unroll
        for (int j = 0; j < 4; j++) {
            zsh[g][lk*4+j][hf*16+lr]    = a0hh[j] + a0lh[j] + a0hl[j];
            zsh[g][16+lk*4+j][hf*16+lr] = a1hh[j] + a1lh[j] + a1hl[j];
        }
        __syncthreads();
        // ---- epilogue: 1024 (batch,unit) cells / 512 threads ----
        unsigned hp0 = 0, hp1 = 0;
        #pragma unroll
        for (int cc = 0; cc < 2; cc++) {
            int cell = tid + cc*512, b = cell >> 5, u = cell & 31;
            float zi = pz[cc][0] + zsh[0][b][u];
            float zf = pz[cc][1] + zsh[1][b][u];
            float zg = pz[cc][2] + zsh[2][b][u];
            float zo = pz[cc][3] + zsh[3][b][u];
            float cold = cc ? c1 : c0;
            float cn = sigmoidf_(zf)*cold + sigmoidf_(zi)*tanhf(zg);
            float hn = sigmoidf_(zo)*tanhf(cn);
            unsigned pk = packbf3(hn);
            if (cc) { c1 = cn; hp1 = pk; } else { c0 = cn; hp0 = pk; }
            hb[(size_t)(t&1)*(NB*NH) + b*NH + chunk*32 + u] = pk;
        }
        // barrier drains all waves' hb stores (implicit vmcnt(0)) + protects zsh
        __syncthreads();
        if (tid == 0)
            __hip_atomic_store(&flag[chunk*16], (unsigned)(t+1),
                               __ATOMIC_RELEASE, __HIP_MEMORY_SCOPE_AGENT);
        // packed h output for downstream GEMMs (off critical path)
        #pragma unroll
        for (int cc = 0; cc < 2; cc++) {
            int cell = tid + cc*512, b = cell >> 5, u = cell & 31;
            hpack[((size_t)(b*NS + t_eff))*NIN1 + dir*NH + chunk*32 + u] = cc ? hp1 : hp0;
        }
    }
}

// ---------------- emissions: em = hid1 @ lin2W^T + b2 ----------------
__global__ __launch_bounds__(256) void k_lin2(const float* __restrict__ hid,
    const float* __restrict__ W2, const float* __restrict__ b2, float* __restrict__ em)
{
    int flat = blockIdx.x*256 + threadIdx.x;
    if (flat >= NBS*NT) return;
    int m = flat / NT, j = flat % NT;
    const float* hr = hid + (size_t)m*NHID;
    const float* wr = W2 + j*NHID;
    float acc = b2[j];
    #pragma unroll 8
    for (int k = 0; k < NHID; k += 4) {
        float4 h4 = *(const float4*)(hr+k);
        float4 w4 = *(const float4*)(wr+k);
        acc += h4.x*w4.x + h4.y*w4.y + h4.z*w4.z + h4.w*w4.w;
    }
    em[flat] = acc;
}

// ---------------- viterbi decode (one wave per batch item) ----------------
__global__ __launch_bounds__(64) void k_viterbi(const float* __restrict__ em,
    const float* __restrict__ start, const float* __restrict__ endv,
    const float* __restrict__ trans, float* __restrict__ dec)
{
    __shared__ float sc[NT];
    __shared__ float tr[NT][NT];
    __shared__ unsigned char hist[NS][NT];
    int b = blockIdx.x, tid = threadIdx.x;
    for (int i = tid; i < NT*NT; i += 64) tr[i/NT][i%NT] = trans[i];
    if (tid < NT) sc[tid] = start[tid] + em[((size_t)b*NS)*NT + tid];
    __syncthreads();
    for (int t = 1; t < NS; t++) {
        float best = -1e30f; int bi = 0;
        if (tid < NT) {
            for (int i = 0; i < NT; i++) {
                float v = sc[i] + tr[i][tid];
                if (v > best) { best = v; bi = i; }
            }
            hist[t][tid] = (unsigned char)bi;
            best += em[((size_t)b*NS + t)*NT + tid];
        }
        __syncthreads();
        if (tid < NT) sc[tid] = best;
        __syncthreads();
    }
    if (tid == 0) {
        float bv = sc[0] + endv[0]; int tag = 0;
        for (int j = 1; j < NT; j++) { float v = sc[j] + endv[j]; if (v > bv) { bv = v; tag = j; } }
        dec[b*NS + NS-1] = (float)tag;
        for (int t = NS-1; t >= 1; t--) { tag = hist[t][tag]; dec[b*NS + t-1] = (float)tag; }
    }
}

// ---------------- CRF NLL (mask is all ones) ----------------
__global__ __launch_bounds__(64) void k_nll(const float* __restrict__ em,
    const int* __restrict__ tags, const float* __restrict__ start,
    const float* __restrict__ endv, const float* __restrict__ trans,
    float* __restrict__ partial)
{
    __shared__ float sc[NT];
    __shared__ float tr[NT][NT];
    int b = blockIdx.x, tid = threadIdx.x;
    for (int i = tid; i < NT*NT; i += 64) tr[i/NT][i%NT] = trans[i];
    if (tid < NT) sc[tid] = start[tid] + em[((size_t)b*NS)*NT + tid];
    __syncthreads();
    for (int t = 1; t < NS; t++) {
        float nv = 0.f;
        if (tid < NT) {
            float m = -1e30f;
            for (int i = 0; i < NT; i++) m = fmaxf(m, sc[i] + tr[i][tid]);
            float s = 0.f;
            for (int i = 0; i < NT; i++) s += expf(sc[i] + tr[i][tid] - m);
            nv = m + logf(s) + em[((size_t)b*NS + t)*NT + tid];
        }
        __syncthreads();
        if (tid < NT) sc[tid] = nv;
        __syncthreads();
    }
    if (tid == 0) {
        float m = -1e30f;
        for (int j = 0; j < NT; j++) m = fmaxf(m, sc[j] + endv[j]);
        float s = 0.f;
        for (int j = 0; j < NT; j++) s += expf(sc[j] + endv[j] - m);
        float logZ = m + logf(s);
        const int* tg = tags + b*NS;
        float num = start[tg[0]] + em[((size_t)b*NS)*NT + tg[0]];
        for (int t = 1; t < NS; t++)
            num += tr[tg[t-1]][tg[t]] + em[((size_t)b*NS + t)*NT + tg[t]];
        num += endv[tg[NS-1]];
        partial[b] = -(num - logZ);
    }
}

__global__ void k_loss_final(const float* __restrict__ partial, float* __restrict__ loss)
{
    if (threadIdx.x == 0 && blockIdx.x == 0) {
        float s = 0.f;
        for (int b = 0; b < NB; b++) s += partial[b];
        *loss = s / (float)(NB*NS);
    }
}

extern "C" void kernel_launch(void* const* d_in, const int* in_sizes, int n_in,
                              void* d_out, int out_size, void* d_ws, size_t ws_size,
                              hipStream_t stream)
{
    const int*   x_word = (const int*)d_in[0];
    const float* x_pos  = (const float*)d_in[1];
    const int*   x_char = (const int*)d_in[2];
    const float* x_enr  = (const float*)d_in[3];
    const int*   y_word = (const int*)d_in[5];
    const float* wembW  = (const float*)d_in[6];
    const float* cembW  = (const float*)d_in[7];
    const float* cnnW   = (const float*)d_in[8];
    const float* cnnb   = (const float*)d_in[9];
    const float* lin1W  = (const float*)d_in[10];
    const float* lin1b  = (const float*)d_in[11];
    const float* lin2W  = (const float*)d_in[12];
    const float* lin2b  = (const float*)d_in[13];
    const float* crf_s  = (const float*)d_in[14];
    const float* crf_e  = (const float*)d_in[15];
    const float* crf_tr = (const float*)d_in[16];
    const float* l0f_Wih = (const float*)d_in[17];
    const float* l0f_Whh = (const float*)d_in[18];
    const float* l0f_b   = (const float*)d_in[19];
    const float* l0b_Wih = (const float*)d_in[20];
    const float* l0b_Whh = (const float*)d_in[21];
    const float* l0b_b   = (const float*)d_in[22];
    const float* l1f_Wih = (const float*)d_in[23];
    const float* l1f_Whh = (const float*)d_in[24];
    const float* l1f_b   = (const float*)d_in[25];
    const float* l1b_Wih = (const float*)d_in[26];
    const float* l1b_Whh = (const float*)d_in[27];
    const float* l1b_b   = (const float*)d_in[28];

    unsigned* ws = (unsigned*)d_ws;   // elements are 4B; mix of u32 and f32 views
    size_t off = 0;
    unsigned* xwp  = ws + off; off += (size_t)NBS*NIN0P;     // packed features
    unsigned* w0fp = ws + off; off += (size_t)NG4*NIN0P;
    unsigned* w0bp = ws + off; off += (size_t)NG4*NIN0P;
    unsigned* w1fp = ws + off; off += (size_t)NG4*NIN1;
    unsigned* w1bp = ws + off; off += (size_t)NG4*NIN1;
    unsigned* wl1p = ws + off; off += (size_t)NHID*NIN1;
    float*    zxf  = (float*)(ws + off); off += (size_t)NBS*NG4;
    float*    zxb  = (float*)(ws + off); off += (size_t)NBS*NG4;
    unsigned* h0p  = ws + off; off += (size_t)NBS*NIN1;
    unsigned* h1p  = ws + off; off += (size_t)NBS*NIN1;
    float*    hid1 = (float*)(ws + off); off += (size_t)NBS*NHID;
    float*    partial = (float*)(ws + off); off += 64;
    unsigned* hbf  = ws + off; off += (size_t)2*2*NB*NH;     // packed h ring
    unsigned* flags= ws + off; off += (size_t)2*NCHUNK*16;

    float* em_out   = (float*)d_out;
    float* dec_out  = em_out + (size_t)NBS*NT;
    float* loss_out = dec_out + NBS;

    // 1. pack weights (one-time per launch)
    k_pack_w<<<(NG4*NIN0P+255)/256, 256, 0, stream>>>(l0f_Wih, w0fp, NG4, NIN0, NIN0P);
    k_pack_w<<<(NG4*NIN0P+255)/256, 256, 0, stream>>>(l0b_Wih, w0bp, NG4, NIN0, NIN0P);
    k_pack_w<<<(NG4*NIN1+255)/256, 256, 0, stream>>>(l1f_Wih, w1fp, NG4, NIN1, NIN1);
    k_pack_w<<<(NG4*NIN1+255)/256, 256, 0, stream>>>(l1b_Wih, w1bp, NG4, NIN1, NIN1);
    k_pack_w<<<(NHID*NIN1+255)/256, 256, 0, stream>>>(lin1W, wl1p, NHID, NIN1, NIN1);
    // 2. features (packed)
    k_features<<<NBS, 128, 0, stream>>>(x_word, x_pos, x_char, x_enr, wembW, cembW, cnnW, cnnb, xwp);
    // 3. layer-0 input projections (bf16x3 MFMA)
    k_gemm_bf3<<<dim3(NBS/128, NG4/128), 256, 0, stream>>>(xwp, w0fp, l0f_b, zxf, NBS, NG4, NIN0P);
    k_gemm_bf3<<<dim3(NBS/128, NG4/128), 256, 0, stream>>>(xwp, w0bp, l0b_b, zxb, NBS, NG4, NIN0P);
    // 4. layer-0 recurrence
    hipMemsetAsync(flags, 0, (size_t)2*NCHUNK*16*sizeof(unsigned), stream);
    k_lstm_layer<<<dim3(NCHUNK, 2), 512, 0, stream>>>(zxf, zxb, l0f_Whh, l0b_Whh, h0p, hbf, flags);
    // 5. layer-1 input projections
    k_gemm_bf3<<<dim3(NBS/128, NG4/128), 256, 0, stream>>>(h0p, w1fp, l1f_b, zxf, NBS, NG4, NIN1);
    k_gemm_bf3<<<dim3(NBS/128, NG4/128), 256, 0, stream>>>(h0p, w1bp, l1b_b, zxb, NBS, NG4, NIN1);
    // 6. layer-1 recurrence
    hipMemsetAsync(flags, 0, (size_t)2*NCHUNK*16*sizeof(unsigned), stream);
    k_lstm_layer<<<dim3(NCHUNK, 2), 512, 0, stream>>>(zxf, zxb, l1f_Whh, l1b_Whh, h1p, hbf, flags);
    // 7. head
    k_gemm_bf3<<<dim3(NBS/128, NHID/128), 256, 0, stream>>>(h1p, wl1p, lin1b, hid1, NBS, NHID, NIN1);
    k_lin2<<<(NBS*NT+255)/256, 256, 0, stream>>>(hid1, lin2W, lin2b, em_out);
    // 8. CRF
    k_viterbi<<<NB, 64, 0, stream>>>(em_out, crf_s, crf_e, crf_tr, dec_out);
    k_nll<<<NB, 64, 0, stream>>>(em_out, y_word, crf_s, crf_e, crf_tr, partial);
    k_loss_final<<<1, 64, 0, stream>>>(partial, loss_out);
}

// Round 6
// 5519.273 us; speedup vs baseline: 2.2426x; 2.2426x over previous
//
#include <hip/hip_runtime.h>
#include <hip/hip_bf16.h>
#include <math.h>

// ---- problem dims ----
constexpr int NB   = 32;
constexpr int NS   = 256;
constexpr int NLC  = 16;
constexpr int NWD  = 256;
constexpr int NCD  = 124;
constexpr int NCO  = 32;
constexpr int NPOS = 36;
constexpr int NENR = 7;
constexpr int NH   = 512;
constexpr int NT   = 18;
constexpr int NIN0 = 331;
constexpr int NIN0P= 352;    // padded to x32 for BK=32
constexpr int NIN1 = 1024;
constexpr int NBS  = NB*NS;  // 8192
constexpr int NG4  = 4*NH;   // 2048
constexpr int NHID = 128;
constexpr int NCHUNK = 16;   // unit-chunks per dir (32 units each)

typedef __attribute__((ext_vector_type(8))) short short8v;
typedef __attribute__((ext_vector_type(4))) float f32x4;

__device__ __forceinline__ float sigmoidf_(float x){ return 1.0f/(1.0f+expf(-x)); }
__device__ __forceinline__ short f2bf(float f) {
    union { __hip_bfloat16 h; short s; } u;
    u.h = __float2bfloat16(f);
    return u.s;
}
__device__ __forceinline__ float bf2f(short s) {
    union { unsigned u; float f; } v;
    v.u = ((unsigned)(unsigned short)s) << 16;
    return v.f;
}
__device__ __forceinline__ unsigned packbf3(float v) {
    short hi = f2bf(v);
    short lo = f2bf(v - bf2f(hi));
    return ((unsigned)(unsigned short)hi << 16) | (unsigned short)lo;
}
// 8 packed u32 (elems k..k+7) -> hi/lo bf16 fragments
__device__ __forceinline__ void unpack8(const unsigned* w, short8v& hi, short8v& lo) {
    union U { short8v s; unsigned u[4]; } H, L;
    #pragma unroll
    for (int i = 0; i < 4; i++) {
        H.u[i] = (w[2*i+1] & 0xFFFF0000u) | (w[2*i] >> 16);
        L.u[i] = (w[2*i+1] << 16) | (w[2*i] & 0xFFFFu);
    }
    hi = H.s; lo = L.s;
}
// relaxed agent-scope ops: compile to global_load/store sc1 — NO buffer_inv/wbl2
__device__ __forceinline__ unsigned ld_sc1(const unsigned* p) {
    return __hip_atomic_load(p, __ATOMIC_RELAXED, __HIP_MEMORY_SCOPE_AGENT);
}
__device__ __forceinline__ void st_sc1(unsigned* p, unsigned v) {
    __hip_atomic_store(p, v, __ATOMIC_RELAXED, __HIP_MEMORY_SCOPE_AGENT);
}

// ---------------- features: word embed + char CNN + concat + relu -> packed u32 ----
__global__ __launch_bounds__(128) void k_features(const int* __restrict__ x_word,
    const float* __restrict__ x_pos, const int* __restrict__ x_char,
    const float* __restrict__ x_enr, const float* __restrict__ wembW,
    const float* __restrict__ cembW, const float* __restrict__ cnnW,
    const float* __restrict__ cnnb, unsigned* __restrict__ xout)
{
    __shared__ float ce[NLC][NCD];
    __shared__ float cv[NCO][13];
    __shared__ float cpool[NCO];
    int n = blockIdx.x;
    int tid = threadIdx.x;
    for (int i = tid; i < NLC*NCD; i += 128) {
        int l = i / NCD, c = i % NCD;
        ce[l][c] = cembW[x_char[n*NLC + l]*NCD + c];
    }
    __syncthreads();
    for (int p = tid; p < NCO*12; p += 128) {
        int o = p & 31, t = p >> 5;
        const float* wr = cnnW + o*NCD*5;
        float acc = 0.f;
        for (int c = 0; c < NCD; c++) {
            #pragma unroll
            for (int k = 0; k < 5; k++) acc += ce[t+k][c] * wr[c*5+k];
        }
        cv[o][t] = acc;
    }
    __syncthreads();
    if (tid < NCO) {
        float m = cv[tid][0];
        #pragma unroll
        for (int t = 1; t < 12; t++) m = fmaxf(m, cv[tid][t]);
        cpool[tid] = m + cnnb[tid];
    }
    __syncthreads();
    int widx = x_word[n];
    unsigned* xr = xout + (size_t)n * NIN0P;
    for (int j = tid; j < NIN0P; j += 128) {
        float v;
        if (j < NWD)            v = wembW[(size_t)widx*NWD + j];
        else if (j < NWD+NPOS)  v = x_pos[n*NPOS + (j-NWD)];
        else if (j < NWD+NPOS+NCO) v = cpool[j-(NWD+NPOS)];
        else if (j < NIN0)      v = x_enr[n*NENR + (j-(NWD+NPOS+NCO))];
        else                    v = 0.f;   // K pad
        xr[j] = packbf3(fmaxf(v, 0.f));
    }
}

// ---------------- pack f32 weight [N][Ksrc] -> packed u32 [N][Kdst] (zero pad) ----
__global__ void k_pack_w(const float* __restrict__ W, unsigned* __restrict__ out,
                         int N, int Ksrc, int Kdst)
{
    int idx = blockIdx.x*256 + threadIdx.x;
    if (idx >= N*Kdst) return;
    int n = idx / Kdst, k = idx % Kdst;
    float v = (k < Ksrc) ? W[(size_t)n*Ksrc + k] : 0.f;
    out[idx] = packbf3(v);
}

// ---------------- bf16x3 MFMA GEMM: C[M,N] = A@W^T + bias ----------------
constexpr int TBK = 32;
constexpr int LSTR = 36;
__global__ __launch_bounds__(256, 2) void k_gemm_bf3(
    const unsigned* __restrict__ A, const unsigned* __restrict__ W,
    const float* __restrict__ bias, float* __restrict__ C,
    int M, int N, int K)
{
    __shared__ unsigned Asl[128*LSTR];
    __shared__ unsigned Bsl[128*LSTR];
    int bm = blockIdx.x*128, bn = blockIdx.y*128;
    int tid = threadIdx.x;
    int l = tid & 63, wv = tid >> 6;
    int wm = wv >> 1, wn = wv & 1;
    int lr = l & 15, lk = l >> 4;

    f32x4 acc[4][4];
    #pragma unroll
    for (int i = 0; i < 4; i++)
        #pragma unroll
        for (int j = 0; j < 4; j++) acc[i][j] = (f32x4){0.f,0.f,0.f,0.f};

    uint4 ra[4], rb[4];
    int KT = K / TBK;
    #pragma unroll
    for (int i = 0; i < 4; i++) {
        int idx = i*256 + tid, row = idx >> 3, c4 = (idx & 7)*4;
        ra[i] = *(const uint4*)(A + (size_t)(bm+row)*K + c4);
        rb[i] = *(const uint4*)(W + (size_t)(bn+row)*K + c4);
    }
    for (int kt = 0; kt < KT; kt++) {
        #pragma unroll
        for (int i = 0; i < 4; i++) {
            int idx = i*256 + tid, row = idx >> 3, c4 = (idx & 7)*4;
            *(uint4*)&Asl[row*LSTR + c4] = ra[i];
            *(uint4*)&Bsl[row*LSTR + c4] = rb[i];
        }
        __syncthreads();
        if (kt+1 < KT) {
            #pragma unroll
            for (int i = 0; i < 4; i++) {
                int idx = i*256 + tid, row = idx >> 3, c4 = (idx & 7)*4;
                ra[i] = *(const uint4*)(A + (size_t)(bm+row)*K + (kt+1)*TBK + c4);
                rb[i] = *(const uint4*)(W + (size_t)(bn+row)*K + (kt+1)*TBK + c4);
            }
        }
        short8v Ah[4], Al_[4], Bh[4], Bl[4];
        #pragma unroll
        for (int f = 0; f < 4; f++) {
            unsigned w8[8];
            int rowA = wm*64 + f*16 + lr;
            *(uint4*)&w8[0] = *(const uint4*)&Asl[rowA*LSTR + lk*8];
            *(uint4*)&w8[4] = *(const uint4*)&Asl[rowA*LSTR + lk*8 + 4];
            unpack8(w8, Ah[f], Al_[f]);
            int rowB = wn*64 + f*16 + lr;
            *(uint4*)&w8[0] = *(const uint4*)&Bsl[rowB*LSTR + lk*8];
            *(uint4*)&w8[4] = *(const uint4*)&Bsl[rowB*LSTR + lk*8 + 4];
            unpack8(w8, Bh[f], Bl[f]);
        }
        #pragma unroll
        for (int i = 0; i < 4; i++)
            #pragma unroll
            for (int j = 0; j < 4; j++) {
                acc[i][j] = __builtin_amdgcn_mfma_f32_16x16x32_bf16(Ah[i],  Bh[j], acc[i][j], 0, 0, 0);
                acc[i][j] = __builtin_amdgcn_mfma_f32_16x16x32_bf16(Al_[i], Bh[j], acc[i][j], 0, 0, 0);
                acc[i][j] = __builtin_amdgcn_mfma_f32_16x16x32_bf16(Ah[i],  Bl[j], acc[i][j], 0, 0, 0);
            }
        __syncthreads();
    }
    #pragma unroll
    for (int i = 0; i < 4; i++) {
        int m0 = bm + wm*64 + i*16 + lk*4;
        #pragma unroll
        for (int j = 0; j < 4; j++) {
            int n0 = bn + wn*64 + j*16 + lr;
            float bv = bias[n0];
            #pragma unroll
            for (int q = 0; q < 4; q++)
                C[(size_t)(m0+q)*N + n0] = acc[i][j][q] + bv;
        }
    }
}

// ---------------- persistent LSTM layer: 16 chunks x 2 dirs, 512 thr ----------
// 8 waves = 4 gates x 2 K-halves (split-K). Split-bf16 weight-stationary MFMA.
// Cross-block exchange: RELAXED agent-scope (sc1) loads/stores ONLY — no
// buffer_inv / buffer_wbl2. Ordering: data sc1-stores -> s_waitcnt vmcnt(0)
// -> barrier -> flag sc1-store. Readers poll flag sc1, then sc1-load data
// (hb lines never live in L2, so no invalidation needed; zx stays L2-warm).
__global__ __launch_bounds__(512, 2) void k_lstm_layer(
    const float* __restrict__ zx_f, const float* __restrict__ zx_b,
    const float* __restrict__ Whh_f, const float* __restrict__ Whh_b,
    unsigned* __restrict__ hpack, unsigned* __restrict__ hbf,
    unsigned* __restrict__ flags)
{
    int chunk = blockIdx.x;        // 0..15 (32 hidden units each)
    int dir   = blockIdx.y;
    int tid = threadIdx.x;
    int wv = tid >> 6, l = tid & 63;
    int g  = wv & 3;               // gate
    int ks = wv >> 2;              // K-half (0/1)
    int lr = l & 15, lk = l >> 4;
    const float* zx  = dir ? zx_b  : zx_f;
    const float* Whh = dir ? Whh_b : Whh_f;
    unsigned* hb = hbf + (size_t)dir * (2*NB*NH);     // [slot][b][k] packed u32
    unsigned* flag = flags + (size_t)dir * NCHUNK * 16;

    // ---- preload Whh slice: gate g, units chunk*32+uh*16+lr, k-half ks ----
    short8v bwh[2][8], bwl[2][8];
    #pragma unroll
    for (int uh = 0; uh < 2; uh++) {
        const float* wrow = Whh + ((size_t)(g*NH + chunk*32 + uh*16 + lr))*NH + ks*256 + lk*8;
        #pragma unroll
        for (int kt = 0; kt < 8; kt++) {
            float u[8];
            *(float4*)&u[0] = *(const float4*)(wrow + kt*32);
            *(float4*)&u[4] = *(const float4*)(wrow + kt*32 + 4);
            short8v sh, sl;
            #pragma unroll
            for (int j = 0; j < 8; j++) {
                short hi = f2bf(u[j]);
                sh[j] = hi;
                sl[j] = f2bf(u[j] - bf2f(hi));
            }
            bwh[uh][kt] = sh; bwl[uh][kt] = sl;
        }
    }

    __shared__ unsigned hstage[32*516];      // h_prev staged once per block
    __shared__ float zsh[2][4][32][33];      // [ks][gate][batch][unit] partials
    float c0 = 0.f, c1 = 0.f;

    for (int t = 0; t < NS; t++) {
        int t_eff = dir ? (NS-1-t) : t;

        // ---- prefetch zx into regs (independent of the flag; L2-warm) ----
        float pz[2][4];
        #pragma unroll
        for (int cc = 0; cc < 2; cc++) {
            int cell = tid + cc*512, b = cell >> 5, u = cell & 31;
            const float* zr = zx + ((size_t)(b*NS + t_eff))*NG4 + chunk*32 + u;
            #pragma unroll
            for (int g2 = 0; g2 < 4; g2++) pz[cc][g2] = zr[g2*NH];
        }

        if (t > 0) {
            // ---- poll all 16 chunk flags (relaxed sc1, no inv) ----
            const unsigned* fp = &flag[(l & 15)*16];
            unsigned v;
            do { v = ld_sc1(fp); } while (!__all((int)(v >= (unsigned)t)));
            asm volatile("" ::: "memory");
            // ---- stage hb slot -> LDS (coalesced sc1 dword loads) ----
            const unsigned* hp = hb + ((t-1)&1)*(NB*NH);
            #pragma unroll
            for (int hh = 0; hh < 4; hh++) {
                unsigned sv0, sv1, sv2, sv3, sv4, sv5, sv6, sv7;
                sv0 = ld_sc1(hp + (hh*8+0)*512 + tid);
                sv1 = ld_sc1(hp + (hh*8+1)*512 + tid);
                sv2 = ld_sc1(hp + (hh*8+2)*512 + tid);
                sv3 = ld_sc1(hp + (hh*8+3)*512 + tid);
                sv4 = ld_sc1(hp + (hh*8+4)*512 + tid);
                sv5 = ld_sc1(hp + (hh*8+5)*512 + tid);
                sv6 = ld_sc1(hp + (hh*8+6)*512 + tid);
                sv7 = ld_sc1(hp + (hh*8+7)*512 + tid);
                hstage[(hh*8+0)*516 + tid] = sv0;
                hstage[(hh*8+1)*516 + tid] = sv1;
                hstage[(hh*8+2)*516 + tid] = sv2;
                hstage[(hh*8+3)*516 + tid] = sv3;
                hstage[(hh*8+4)*516 + tid] = sv4;
                hstage[(hh*8+5)*516 + tid] = sv5;
                hstage[(hh*8+6)*516 + tid] = sv6;
                hstage[(hh*8+7)*516 + tid] = sv7;
            }
        }
        __syncthreads();   // barrier A: stage visible

        // ---- split-K MFMA: this wave covers k in [ks*256, ks*256+256) ----
        f32x4 acc[2][2][3];
        #pragma unroll
        for (int bh = 0; bh < 2; bh++)
            #pragma unroll
            for (int uh = 0; uh < 2; uh++)
                #pragma unroll
                for (int q = 0; q < 3; q++) acc[bh][uh][q] = (f32x4){0.f,0.f,0.f,0.f};
        if (t > 0) {
            #pragma unroll
            for (int kt = 0; kt < 8; kt++) {
                short8v ah[2], al[2];
                #pragma unroll
                for (int bh = 0; bh < 2; bh++) {
                    unsigned w8[8];
                    const unsigned* sp = hstage + (bh*16+lr)*516 + ks*256 + kt*32 + lk*8;
                    *(uint4*)&w8[0] = *(const uint4*)sp;
                    *(uint4*)&w8[4] = *(const uint4*)(sp+4);
                    unpack8(w8, ah[bh], al[bh]);
                }
                #pragma unroll
                for (int bh = 0; bh < 2; bh++)
                    #pragma unroll
                    for (int uh = 0; uh < 2; uh++) {
                        acc[bh][uh][0] = __builtin_amdgcn_mfma_f32_16x16x32_bf16(ah[bh], bwh[uh][kt], acc[bh][uh][0], 0, 0, 0);
                        acc[bh][uh][1] = __builtin_amdgcn_mfma_f32_16x16x32_bf16(al[bh], bwh[uh][kt], acc[bh][uh][1], 0, 0, 0);
                        acc[bh][uh][2] = __builtin_amdgcn_mfma_f32_16x16x32_bf16(ah[bh], bwl[uh][kt], acc[bh][uh][2], 0, 0, 0);
                    }
            }
        }
        // C layout: col=lane&15 -> unit uh*16+lr, row=(lane>>4)*4+j -> batch
        #pragma unroll
        for (int bh = 0; bh < 2; bh++)
            #pragma unroll
            for (int uh = 0; uh < 2; uh++)
                #pragma unroll
                for (int j = 0; j < 4; j++)
                    zsh[ks][g][bh*16 + lk*4 + j][uh*16 + lr] =
                        acc[bh][uh][0][j] + acc[bh][uh][1][j] + acc[bh][uh][2][j];
        __syncthreads();   // barrier B: zsh ready

        // ---- epilogue: 1024 cells / 512 threads ----
        unsigned hq0 = 0, hq1 = 0;
        #pragma unroll
        for (int cc = 0; cc < 2; cc++) {
            int cell = tid + cc*512, b = cell >> 5, u = cell & 31;
            float zi = pz[cc][0] + zsh[0][0][b][u] + zsh[1][0][b][u];
            float zf = pz[cc][1] + zsh[0][1][b][u] + zsh[1][1][b][u];
            float zg = pz[cc][2] + zsh[0][2][b][u] + zsh[1][2][b][u];
            float zo = pz[cc][3] + zsh[0][3][b][u] + zsh[1][3][b][u];
            float cold = cc ? c1 : c0;
            float cn = sigmoidf_(zf)*cold + sigmoidf_(zi)*tanhf(zg);
            float hn = sigmoidf_(zo)*tanhf(cn);
            unsigned pk = packbf3(hn);
            if (cc) { c1 = cn; hq1 = pk; } else { c0 = cn; hq0 = pk; }
            st_sc1(&hb[(size_t)(t&1)*(NB*NH) + b*NH + chunk*32 + u], pk);
        }
        asm volatile("s_waitcnt vmcnt(0)" ::: "memory");  // hb stores acked at MALL
        __syncthreads();   // barrier C: all waves' stores drained
        if (tid == 0) st_sc1(&flag[chunk*16], (unsigned)(t+1));
        // packed h for downstream GEMMs (off critical path, plain stores)
        #pragma unroll
        for (int cc = 0; cc < 2; cc++) {
            int cell = tid + cc*512, b = cell >> 5, u = cell & 31;
            hpack[((size_t)(b*NS + t_eff))*NIN1 + dir*NH + chunk*32 + u] = cc ? hq1 : hq0;
        }
    }
}

// ---------------- emissions: em = hid1 @ lin2W^T + b2 ----------------
__global__ __launch_bounds__(256) void k_lin2(const float* __restrict__ hid,
    const float* __restrict__ W2, const float* __restrict__ b2, float* __restrict__ em)
{
    int flat = blockIdx.x*256 + threadIdx.x;
    if (flat >= NBS*NT) return;
    int m = flat / NT, j = flat % NT;
    const float* hr = hid + (size_t)m*NHID;
    const float* wr = W2 + j*NHID;
    float acc = b2[j];
    #pragma unroll 8
    for (int k = 0; k < NHID; k += 4) {
        float4 h4 = *(const float4*)(hr+k);
        float4 w4 = *(const float4*)(wr+k);
        acc += h4.x*w4.x + h4.y*w4.y + h4.z*w4.z + h4.w*w4.w;
    }
    em[flat] = acc;
}

// ---------------- viterbi decode (one wave per batch item) ----------------
__global__ __launch_bounds__(64) void k_viterbi(const float* __restrict__ em,
    const float* __restrict__ start, const float* __restrict__ endv,
    const float* __restrict__ trans, float* __restrict__ dec)
{
    __shared__ float sc[NT];
    __shared__ float tr[NT][NT];
    __shared__ unsigned char hist[NS][NT];
    int b = blockIdx.x, tid = threadIdx.x;
    for (int i = tid; i < NT*NT; i += 64) tr[i/NT][i%NT] = trans[i];
    if (tid < NT) sc[tid] = start[tid] + em[((size_t)b*NS)*NT + tid];
    __syncthreads();
    for (int t = 1; t < NS; t++) {
        float best = -1e30f; int bi = 0;
        if (tid < NT) {
            for (int i = 0; i < NT; i++) {
                float v = sc[i] + tr[i][tid];
                if (v > best) { best = v; bi = i; }
            }
            hist[t][tid] = (unsigned char)bi;
            best += em[((size_t)b*NS + t)*NT + tid];
        }
        __syncthreads();
        if (tid < NT) sc[tid] = best;
        __syncthreads();
    }
    if (tid == 0) {
        float bv = sc[0] + endv[0]; int tag = 0;
        for (int j = 1; j < NT; j++) { float v = sc[j] + endv[j]; if (v > bv) { bv = v; tag = j; } }
        dec[b*NS + NS-1] = (float)tag;
        for (int t = NS-1; t >= 1; t--) { tag = hist[t][tag]; dec[b*NS + t-1] = (float)tag; }
    }
}

// ---------------- CRF NLL (mask is all ones) ----------------
__global__ __launch_bounds__(64) void k_nll(const float* __restrict__ em,
    const int* __restrict__ tags, const float* __restrict__ start,
    const float* __restrict__ endv, const float* __restrict__ trans,
    float* __restrict__ partial)
{
    __shared__ float sc[NT];
    __shared__ float tr[NT][NT];
    int b = blockIdx.x, tid = threadIdx.x;
    for (int i = tid; i < NT*NT; i += 64) tr[i/NT][i%NT] = trans[i];
    if (tid < NT) sc[tid] = start[tid] + em[((size_t)b*NS)*NT + tid];
    __syncthreads();
    for (int t = 1; t < NS; t++) {
        float nv = 0.f;
        if (tid < NT) {
            float m = -1e30f;
            for (int i = 0; i < NT; i++) m = fmaxf(m, sc[i] + tr[i][tid]);
            float s = 0.f;
            for (int i = 0; i < NT; i++) s += expf(sc[i] + tr[i][tid] - m);
            nv = m + logf(s) + em[((size_t)b*NS + t)*NT + tid];
        }
        __syncthreads();
        if (tid < NT) sc[tid] = nv;
        __syncthreads();
    }
    if (tid == 0) {
        float m = -1e30f;
        for (int j = 0; j < NT; j++) m = fmaxf(m, sc[j] + endv[j]);
        float s = 0.f;
        for (int j = 0; j < NT; j++) s += expf(sc[j] + endv[j] - m);
        float logZ = m + logf(s);
        const int* tg = tags + b*NS;
        float num = start[tg[0]] + em[((size_t)b*NS)*NT + tg[0]];
        for (int t = 1; t < NS; t++)
            num += tr[tg[t-1]][tg[t]] + em[((size_t)b*NS + t)*NT + tg[t]];
        num += endv[tg[NS-1]];
        partial[b] = -(num - logZ);
    }
}

__global__ void k_loss_final(const float* __restrict__ partial, float* __restrict__ loss)
{
    if (threadIdx.x == 0 && blockIdx.x == 0) {
        float s = 0.f;
        for (int b = 0; b < NB; b++) s += partial[b];
        *loss = s / (float)(NB*NS);
    }
}

extern "C" void kernel_launch(void* const* d_in, const int* in_sizes, int n_in,
                              void* d_out, int out_size, void* d_ws, size_t ws_size,
                              hipStream_t stream)
{
    const int*   x_word = (const int*)d_in[0];
    const float* x_pos  = (const float*)d_in[1];
    const int*   x_char = (const int*)d_in[2];
    const float* x_enr  = (const float*)d_in[3];
    const int*   y_word = (const int*)d_in[5];
    const float* wembW  = (const float*)d_in[6];
    const float* cembW  = (const float*)d_in[7];
    const float* cnnW   = (const float*)d_in[8];
    const float* cnnb   = (const float*)d_in[9];
    const float* lin1W  = (const float*)d_in[10];
    const float* lin1b  = (const float*)d_in[11];
    const float* lin2W  = (const float*)d_in[12];
    const float* lin2b  = (const float*)d_in[13];
    const float* crf_s  = (const float*)d_in[14];
    const float* crf_e  = (const float*)d_in[15];
    const float* crf_tr = (const float*)d_in[16];
    const float* l0f_Wih = (const float*)d_in[17];
    const float* l0f_Whh = (const float*)d_in[18];
    const float* l0f_b   = (const float*)d_in[19];
    const float* l0b_Wih = (const float*)d_in[20];
    const float* l0b_Whh = (const float*)d_in[21];
    const float* l0b_b   = (const float*)d_in[22];
    const float* l1f_Wih = (const float*)d_in[23];
    const float* l1f_Whh = (const float*)d_in[24];
    const float* l1f_b   = (const float*)d_in[25];
    const float* l1b_Wih = (const float*)d_in[26];
    const float* l1b_Whh = (const float*)d_in[27];
    const float* l1b_b   = (const float*)d_in[28];

    unsigned* ws = (unsigned*)d_ws;
    size_t off = 0;
    unsigned* xwp  = ws + off; off += (size_t)NBS*NIN0P;
    unsigned* w0fp = ws + off; off += (size_t)NG4*NIN0P;
    unsigned* w0bp = ws + off; off += (size_t)NG4*NIN0P;
    unsigned* w1fp = ws + off; off += (size_t)NG4*NIN1;
    unsigned* w1bp = ws + off; off += (size_t)NG4*NIN1;
    unsigned* wl1p = ws + off; off += (size_t)NHID*NIN1;
    float*    zxf  = (float*)(ws + off); off += (size_t)NBS*NG4;
    float*    zxb  = (float*)(ws + off); off += (size_t)NBS*NG4;
    unsigned* h0p  = ws + off; off += (size_t)NBS*NIN1;
    unsigned* h1p  = ws + off; off += (size_t)NBS*NIN1;
    float*    hid1 = (float*)(ws + off); off += (size_t)NBS*NHID;
    float*    partial = (float*)(ws + off); off += 64;
    unsigned* hbf  = ws + off; off += (size_t)2*2*NB*NH;
    unsigned* flags= ws + off; off += (size_t)2*NCHUNK*16;

    float* em_out   = (float*)d_out;
    float* dec_out  = em_out + (size_t)NBS*NT;
    float* loss_out = dec_out + NBS;

    // 1. pack weights
    k_pack_w<<<(NG4*NIN0P+255)/256, 256, 0, stream>>>(l0f_Wih, w0fp, NG4, NIN0, NIN0P);
    k_pack_w<<<(NG4*NIN0P+255)/256, 256, 0, stream>>>(l0b_Wih, w0bp, NG4, NIN0, NIN0P);
    k_pack_w<<<(NG4*NIN1+255)/256, 256, 0, stream>>>(l1f_Wih, w1fp, NG4, NIN1, NIN1);
    k_pack_w<<<(NG4*NIN1+255)/256, 256, 0, stream>>>(l1b_Wih, w1bp, NG4, NIN1, NIN1);
    k_pack_w<<<(NHID*NIN1+255)/256, 256, 0, stream>>>(lin1W, wl1p, NHID, NIN1, NIN1);
    // 2. features (packed)
    k_features<<<NBS, 128, 0, stream>>>(x_word, x_pos, x_char, x_enr, wembW, cembW, cnnW, cnnb, xwp);
    // 3. layer-0 input projections
    k_gemm_bf3<<<dim3(NBS/128, NG4/128), 256, 0, stream>>>(xwp, w0fp, l0f_b, zxf, NBS, NG4, NIN0P);
    k_gemm_bf3<<<dim3(NBS/128, NG4/128), 256, 0, stream>>>(xwp, w0bp, l0b_b, zxb, NBS, NG4, NIN0P);
    // 4. layer-0 recurrence
    hipMemsetAsync(flags, 0, (size_t)2*NCHUNK*16*sizeof(unsigned), stream);
    k_lstm_layer<<<dim3(NCHUNK, 2), 512, 0, stream>>>(zxf, zxb, l0f_Whh, l0b_Whh, h0p, hbf, flags);
    // 5. layer-1 input projections
    k_gemm_bf3<<<dim3(NBS/128, NG4/128), 256, 0, stream>>>(h0p, w1fp, l1f_b, zxf, NBS, NG4, NIN1);
    k_gemm_bf3<<<dim3(NBS/128, NG4/128), 256, 0, stream>>>(h0p, w1bp, l1b_b, zxb, NBS, NG4, NIN1);
    // 6. layer-1 recurrence
    hipMemsetAsync(flags, 0, (size_t)2*NCHUNK*16*sizeof(unsigned), stream);
    k_lstm_layer<<<dim3(NCHUNK, 2), 512, 0, stream>>>(zxf, zxb, l1f_Whh, l1b_Whh, h1p, hbf, flags);
    // 7. head
    k_gemm_bf3<<<dim3(NBS/128, NHID/128), 256, 0, stream>>>(h1p, wl1p, lin1b, hid1, NBS, NHID, NIN1);
    k_lin2<<<(NBS*NT+255)/256, 256, 0, stream>>>(hid1, lin2W, lin2b, em_out);
    // 8. CRF
    k_viterbi<<<NB, 64, 0, stream>>>(em_out, crf_s, crf_e, crf_tr, dec_out);
    k_nll<<<NB, 64, 0, stream>>>(em_out, y_word, crf_s, crf_e, crf_tr, partial);
    k_loss_final<<<1, 64, 0, stream>>>(partial, loss_out);
}